// Round 14
// baseline (817.779 us; speedup 1.0000x reference)
//
#include <hip/hip_runtime.h>
#include <stdint.h>

#define T_DIM 512
#define B_DIM 64
#define D_DIM 1024
#define H_DIM 8
#define DH_DIM 128
#define MROWS (T_DIM * B_DIM)   // 32768 rows across all timesteps

typedef unsigned short u16;
typedef __attribute__((ext_vector_type(8))) __bf16 bf16x8;
typedef __attribute__((ext_vector_type(4))) float f32x4;
typedef __attribute__((ext_vector_type(16))) float f32x16;

__device__ __forceinline__ u16 f2bf(float f) {
  union { float f; uint32_t u; } v; v.f = f;
  uint32_t u = v.u;
  u += 0x7fffu + ((u >> 16) & 1u);   // RNE
  return (u16)(u >> 16);
}
__device__ __forceinline__ float bf2f(u16 h) {
  union { uint32_t u; float f; } v; v.u = ((uint32_t)h) << 16;
  return v.f;
}

__device__ __forceinline__ void gload16(const void* g, void* l) {
  __builtin_amdgcn_global_load_lds(
      (const __attribute__((address_space(1))) uint32_t*)g,
      (__attribute__((address_space(3))) uint32_t*)l, 16, 0, 0);
}

#define SB()  __builtin_amdgcn_sched_barrier(0)
#define BAR() __builtin_amdgcn_s_barrier()
#define VM4() asm volatile("s_waitcnt vmcnt(4)" ::: "memory")
#define VM6() asm volatile("s_waitcnt vmcnt(6)" ::: "memory")
#define VM10() asm volatile("s_waitcnt vmcnt(10)" ::: "memory")
#define LGK0() asm volatile("s_waitcnt lgkmcnt(0)" ::: "memory")
#define PRIO1() __builtin_amdgcn_s_setprio(1)
#define PRIO0() __builtin_amdgcn_s_setprio(0)

// ---------------- weight prep (x casts eliminated — gemm1 reads f32 x directly) ----------------

__device__ __forceinline__ void cast8(const float* __restrict__ in, u16* __restrict__ out, size_t i) {
  const float4 a = ((const float4*)in)[i * 2];
  const float4 b = ((const float4*)in)[i * 2 + 1];
  union { u16 h[8]; uint4 u; } o;
  o.h[0] = f2bf(a.x); o.h[1] = f2bf(a.y); o.h[2] = f2bf(a.z); o.h[3] = f2bf(a.w);
  o.h[4] = f2bf(b.x); o.h[5] = f2bf(b.y); o.h[6] = f2bf(b.z); o.h[7] = f2bf(b.w);
  ((uint4*)out)[i] = o.u;
}

// blocks: [0,8192) Wc | [8192,9728) Wqkv | [9728,10240) Wr_out | [10240,10752) Wi_out | [10752,10756) bc
__global__ void prep_cast_kernel(const float* __restrict__ Wr, const float* __restrict__ Wi,
                                 const float* __restrict__ br, const float* __restrict__ bi,
                                 const float* __restrict__ Wqkv,
                                 const float* __restrict__ Wro, const float* __restrict__ Wio,
                                 u16* __restrict__ Wc, float* __restrict__ bc,
                                 u16* __restrict__ Wqkvb, u16* __restrict__ Wob) {
  const int blk = blockIdx.x;
  if (blk < 8192) {                      // Wc[n][k]: (1024,2048) bf16
    const int idx = blk * 256 + threadIdx.x;
    const int n = idx >> 11;
    const int k = idx & 2047;
    const int kk = k & 1023;
    const float a = Wr[n * 1024 + kk], b = Wi[n * 1024 + kk];
    Wc[idx] = f2bf(k < 1024 ? a + b : a - b);
  } else if (blk < 9728) {
    cast8(Wqkv, Wqkvb, (size_t)(blk - 8192) * 256 + threadIdx.x);
  } else if (blk < 10240) {
    cast8(Wro, Wob, (size_t)(blk - 9728) * 256 + threadIdx.x);
  } else if (blk < 10752) {
    cast8(Wio, Wob + (size_t)1024 * 1024, (size_t)(blk - 10240) * 256 + threadIdx.x);
  } else {
    const int i = (blk - 10752) * 256 + threadIdx.x;
    if (i < D_DIM) bc[i] = br[i] + bi[i];
  }
}

// ---------------- shared GEMM pieces ----------------

__device__ __forceinline__ void readF(bf16x8 (&d)[2][2], const u16* s, int rowoff, int la32, int puA) {
#pragma unroll
  for (int mf = 0; mf < 2; ++mf)
#pragma unroll
    for (int kk = 0; kk < 2; ++kk)
      d[mf][kk] = *(const bf16x8*)(s + (rowoff + mf * 32 + la32) * 32 + (puA ^ (kk << 4)));
}

__device__ __forceinline__ void mfma8(f32x16 (&acc)[4][2], const bf16x8 (&a)[2][2],
                                      const bf16x8 (&b)[2][2], int QM) {
#pragma unroll
  for (int kk = 0; kk < 2; ++kk)
#pragma unroll
    for (int mf = 0; mf < 2; ++mf)
#pragma unroll
      for (int nf = 0; nf < 2; ++nf)
        acc[QM * 2 + mf][nf] =
            __builtin_amdgcn_mfma_f32_32x32x16_bf16(a[mf][kk], b[nf][kk], acc[QM * 2 + mf][nf], 0, 0, 0);
}

// ------- gemm1: 8-PHASE schedule with A reg-staged from f32 global -------
// Same slot-write phases as the race-proven R9 8-phase (WAR windows carry over);
// A-stage = {aloadH 4x dwordx4 issued ONE A-PHASE (2 phases) early into arE/arO ping-pong;
// cwriteH cvt+2x ds_write_b128 in the ORIGINAL stage phase; LGK0 before that phase's
// mid-barrier publishes}. B-stage = gload16 x2, guarded by counted vmcnt.
// Queue ledger (A=4, B=2 vmem/stage), steady state verified:
//   entry [a11(4),B10(2)]=6; ph0 cwrite(E) drains a11 -> [B10]; +a(4)=6
//   ph1 +B11(2)=8 | ph2 cwrite(O) drains B10,a00 -> [B11]; +a(4)=6; VM10 no-op
//   ph3 +B00(2)=8; VM6 drains B11 | ph4 cwrite(E) drains a01 -> [B00]; +a(4)=6
//   ph5 +B01(2)=8 | ph6 cwrite(O) drains B00,a10 -> [B01]; +a(4)=6
//   ph7 +B10'(2)=8; VM6 drains B01 -> entry state. All four reader sets covered
//   by {drain + barrier} BEFORE first read. Tail: clamp t->0 keeps counts exact.
__global__ __launch_bounds__(512, 2) void gemm_f32a_kernel(
    const float* __restrict__ A0f, const float* __restrict__ A1f, int kSplit, int lda,
    const u16* __restrict__ Bw, int ldb,
    const float* __restrict__ bias,
    u16* __restrict__ C0, int ldc, int K, int nColBlk)
{
  extern __shared__ u16 lds[];   // 128 KB: [buf:2][ Ak0 | Ak1 | Bk0 | Bk1 ]
  const int tid  = threadIdx.x;
  const int lane = tid & 63;
  const int w    = tid >> 6;
  const int wr   = w >> 2;
  const int wc   = w & 3;

  const int bid   = blockIdx.x;
  const int xcd   = bid & 7;
  const int local = bid >> 3;
  const int rowL  = local / nColBlk;
  const int colB  = local - rowL * nColBlk;
  const size_t rowBase = (size_t)(xcd * 16 + rowL) * 256;
  const size_t colBase = (size_t)colB * 256;

  f32x16 acc[4][2];
#pragma unroll
  for (int i = 0; i < 4; ++i)
#pragma unroll
    for (int j = 0; j < 2; ++j)
#pragma unroll
      for (int e = 0; e < 16; ++e) acc[i][j][e] = 0.f;

  const int NT = K >> 6;
  const int la32 = lane & 31;
  const int g2   = lane >> 5;
  const int f    = (la32 & 3) ^ ((la32 >> 2) & 3);
  const int puA  = ((g2 ^ f) << 3);

  float4 arE[4], arO[4];

  auto aloadH = [&](int ks, int t, auto& ar) {
    if (t >= NT) t = 0;
    const int kb = t * 64;
    const float* Af; int kc;
    if (kb < kSplit) { Af = A0f; kc = kb; } else { Af = A1f; kc = kb - kSplit; }
#pragma unroll
    for (int i2 = 0; i2 < 2; ++i2) {
      const int l = i2 * 512 + tid, r = l >> 2, p = l & 3;
      const int lu = p ^ (r & 3) ^ ((r >> 2) & 3);
      const float* g = Af + (rowBase + r) * (size_t)lda + kc + ks * 32 + lu * 8;
      ar[i2 * 2 + 0] = *(const float4*)g;
      ar[i2 * 2 + 1] = *(const float4*)(g + 4);
    }
  };
  auto cwriteH = [&](int buf, int ks, auto& ar) {
#pragma unroll
    for (int i2 = 0; i2 < 2; ++i2) {
      const int l = i2 * 512 + tid;
      const float4 x0 = ar[i2 * 2 + 0];
      const float4 x1 = ar[i2 * 2 + 1];
      union { u16 h[8]; uint4 u; } o;
      o.h[0] = f2bf(x0.x); o.h[1] = f2bf(x0.y); o.h[2] = f2bf(x0.z); o.h[3] = f2bf(x0.w);
      o.h[4] = f2bf(x1.x); o.h[5] = f2bf(x1.y); o.h[6] = f2bf(x1.z); o.h[7] = f2bf(x1.w);
      *(uint4*)(lds + buf * 32768 + ks * 8192 + (size_t)l * 8) = o.u;
    }
  };
  auto stageB = [&](int buf, int ks, int t) {
    if (t >= NT) t = 0;
    const int kb = t * 64;
    u16* dst = lds + buf * 32768 + 16384 + ks * 8192;
#pragma unroll
    for (int i2 = 0; i2 < 2; ++i2) {
      const int l = i2 * 512 + tid, r = l >> 2, p = l & 3;
      const int lu = p ^ (r & 3) ^ ((r >> 2) & 3);
      gload16(Bw + (colBase + r) * (size_t)ldb + kb + ks * 32 + lu * 8, dst + l * 8);
    }
  };

  const u16* sA_b0k0 = lds;
  const u16* sA_b0k1 = lds + 8192;
  const u16* sB_b0k0 = lds + 16384;
  const u16* sB_b0k1 = lds + 16384 + 8192;
  const u16* sA_b1k0 = lds + 32768;
  const u16* sA_b1k1 = lds + 32768 + 8192;
  const u16* sB_b1k0 = lds + 32768 + 16384;
  const u16* sB_b1k1 = lds + 32768 + 16384 + 8192;
  const int rA0 = wr * 128;
  const int rA1 = wr * 128 + 64;
  const int rB  = wc * 64;

  // prologue: A(t0 both halves)+A(t1 k0) via load+write; B(t0 both)+B(t1 k0) staged;
  // arE <- A(t1 k1) left in flight. Queue after VM6: [a11(4), B10(2)] = steady entry.
  aloadH(0, 0, arE); cwriteH(0, 0, arE);
  aloadH(1, 0, arE); cwriteH(0, 1, arE);
  aloadH(0, 1, arE); cwriteH(1, 0, arE);
  stageB(0, 0, 0); stageB(0, 1, 0);
  aloadH(1, 1, arE);
  stageB(1, 0, 1);
  VM6();     // drains B(0,0),B(0,1); leaves a11(4)+B10(2)
  LGK0();    // publish cwrites
  SB(); BAR(); SB();

  bf16x8 a0[2][2], a1[2][2], bbE[2][2], bbO[2][2];
  const int NIT = NT >> 1;
  for (int i = 0; i < NIT; ++i) {
    const int u = 2 * i, v = 2 * i + 1;
    // ph0 (b0k0,QM0): self a0,bbE + pre a1; A-stage (1,1)<-v
    readF(a0,  sA_b0k0, rA0, la32, puA);
    readF(bbE, sB_b0k0, rB,  la32, puA);
    readF(a1,  sA_b0k0, rA1, la32, puA);
    cwriteH(1, 1, arE);
    aloadH(0, u + 2, arO);
    SB(); LGK0(); BAR(); SB();
    PRIO1(); mfma8(acc, a0, bbE, 0); PRIO0(); SB();
    BAR(); SB();
    // ph1 (b0k0,QM1): pre a0,bbO <- b0k1; B-stage (1,1)<-v
    readF(a0,  sA_b0k1, rA0, la32, puA);
    readF(bbO, sB_b0k1, rB,  la32, puA);
    stageB(1, 1, v);
    SB(); BAR(); SB();
    PRIO1(); mfma8(acc, a1, bbE, 1); PRIO0(); SB();
    BAR(); SB();
    // ph2 (b0k1,QM0): pre a1 <- b0k1; A-stage (0,0)<-u+2
    readF(a1,  sA_b0k1, rA1, la32, puA);
    cwriteH(0, 0, arO);
    aloadH(1, u + 2, arE);
    SB(); LGK0(); BAR(); SB();
    PRIO1(); mfma8(acc, a0, bbO, 0); PRIO0(); SB();
    VM10();   // guards prev ph7's B(1,0,v) for ph3/ph4 (also drained by cwrite's implied wait)
    BAR(); SB();
    // ph3 (b0k1,QM1): pre a0,bbE <- b1k0; B-stage (0,0)<-u+2
    readF(a0,  sA_b1k0, rA0, la32, puA);
    readF(bbE, sB_b1k0, rB,  la32, puA);
    stageB(0, 0, u + 2);
    SB(); BAR(); SB();
    PRIO1(); mfma8(acc, a1, bbO, 1); PRIO0(); SB();
    VM6();    // drains B(1,1,v) -> b1k1 resident for ph5/ph6
    BAR(); SB();
    // ph4 (b1k0,QM0): pre a1 <- b1k0; A-stage (0,1)<-u+2
    readF(a1,  sA_b1k0, rA1, la32, puA);
    cwriteH(0, 1, arE);
    aloadH(0, v + 2, arO);
    SB(); LGK0(); BAR(); SB();
    PRIO1(); mfma8(acc, a0, bbE, 0); PRIO0(); SB();
    BAR(); SB();
    // ph5 (b1k0,QM1): pre a0,bbO <- b1k1; B-stage (0,1)<-u+2
    readF(a0,  sA_b1k1, rA0, la32, puA);
    readF(bbO, sB_b1k1, rB,  la32, puA);
    stageB(0, 1, u + 2);
    SB(); BAR(); SB();
    PRIO1(); mfma8(acc, a1, bbE, 1); PRIO0(); SB();
    BAR(); SB();
    // ph6 (b1k1,QM0): pre a1 <- b1k1; A-stage (1,0)<-v+2
    readF(a1,  sA_b1k1, rA1, la32, puA);
    cwriteH(1, 0, arO);
    aloadH(1, v + 2, arE);
    SB(); LGK0(); BAR(); SB();
    PRIO1(); mfma8(acc, a0, bbO, 0); PRIO0(); SB();
    BAR(); SB();
    // ph7 (b1k1,QM1): B-stage (1,0)<-v+2
    stageB(1, 0, v + 2);
    SB(); BAR(); SB();
    PRIO1(); mfma8(acc, a1, bbO, 1); PRIO0(); SB();
    VM6();    // drains B(0,1,u+2) [B(0,0,u+2) drained at ph6 cwrite] -> buf0 ready
    BAR(); SB();
  }

  // epilogue: bf16 out + bias
#pragma unroll
  for (int mi = 0; mi < 4; ++mi)
#pragma unroll
    for (int ni = 0; ni < 2; ++ni) {
      const int cn = wc * 64 + ni * 32 + la32;
      const float badd = bias[colBase + cn];
      const size_t col = colBase + cn;
#pragma unroll
      for (int r = 0; r < 16; ++r) {
        const size_t row = rowBase + wr * 128 + mi * 32 + (r & 3) + 8 * (r >> 2) + 4 * g2;
        C0[row * (size_t)ldc + col] = f2bf(acc[mi][ni][r] + badd);
      }
    }
}

// ------- 256x256 8-phase bf16 MFMA GEMM (32x32x16) — R9 verified, UNTOUCHED -------

template <int EPI>
__global__ __launch_bounds__(512, 2) void gemm256_kernel(
    const u16* __restrict__ A0, const u16* __restrict__ A1, int kSplit, int lda,
    const u16* __restrict__ Bw, int ldb,
    const float* __restrict__ bias,
    void* __restrict__ C0, void* __restrict__ C1, void* __restrict__ C2,
    int ldc, int K, int nColBlk)
{
  extern __shared__ u16 lds[];
  const int tid  = threadIdx.x;
  const int lane = tid & 63;
  const int w    = tid >> 6;
  const int wr   = w >> 2;
  const int wc   = w & 3;

  const int bid   = blockIdx.x;
  const int xcd   = bid & 7;
  const int local = bid >> 3;
  const int rowL  = local / nColBlk;
  const int colB  = local - rowL * nColBlk;
  const size_t rowBase = (size_t)(xcd * 16 + rowL) * 256;
  const size_t colBase = (size_t)colB * 256;

  f32x16 acc[4][2];
#pragma unroll
  for (int i = 0; i < 4; ++i)
#pragma unroll
    for (int j = 0; j < 2; ++j)
#pragma unroll
      for (int e = 0; e < 16; ++e) acc[i][j][e] = 0.f;

  const int NT = K >> 6;
  const int la32 = lane & 31;
  const int g2   = lane >> 5;
  const int f    = (la32 & 3) ^ ((la32 >> 2) & 3);
  const int puA  = ((g2 ^ f) << 3);

  auto stageA = [&](int buf, int ks, int t) {
    if (t >= NT) t = 0;
    const int kb = t * 64;
    const u16* Ab; int kc;
    if (kb < kSplit) { Ab = A0; kc = kb; } else { Ab = A1; kc = kb - kSplit; }
    u16* dst = lds + buf * 32768 + ks * 8192;
#pragma unroll
    for (int i2 = 0; i2 < 2; ++i2) {
      const int l = i2 * 512 + tid, r = l >> 2, p = l & 3;
      const int lu = p ^ (r & 3) ^ ((r >> 2) & 3);
      gload16(Ab + (rowBase + r) * (size_t)lda + kc + ks * 32 + lu * 8, dst + l * 8);
    }
  };
  auto stageB = [&](int buf, int ks, int t) {
    if (t >= NT) t = 0;
    const int kb = t * 64;
    u16* dst = lds + buf * 32768 + 16384 + ks * 8192;
#pragma unroll
    for (int i2 = 0; i2 < 2; ++i2) {
      const int l = i2 * 512 + tid, r = l >> 2, p = l & 3;
      const int lu = p ^ (r & 3) ^ ((r >> 2) & 3);
      gload16(Bw + (colBase + r) * (size_t)ldb + kb + ks * 32 + lu * 8, dst + l * 8);
    }
  };

  const u16* sA_b0k0 = lds;
  const u16* sA_b0k1 = lds + 8192;
  const u16* sB_b0k0 = lds + 16384;
  const u16* sB_b0k1 = lds + 16384 + 8192;
  const u16* sA_b1k0 = lds + 32768;
  const u16* sA_b1k1 = lds + 32768 + 8192;
  const u16* sB_b1k0 = lds + 32768 + 16384;
  const u16* sB_b1k1 = lds + 32768 + 16384 + 8192;
  const int rA0 = wr * 128;
  const int rA1 = wr * 128 + 64;
  const int rB  = wc * 64;

  stageA(0, 0, 0); stageB(0, 0, 0); stageA(0, 1, 0); stageB(0, 1, 0);
  stageA(1, 0, 1); stageB(1, 0, 1);
  VM4();
  SB(); BAR(); SB();

  bf16x8 a0[2][2], a1[2][2], bbE[2][2], bbO[2][2];
  const int NIT = NT >> 1;
  for (int i = 0; i < NIT; ++i) {
    const int u = 2 * i, v = 2 * i + 1;
    readF(a0,  sA_b0k0, rA0, la32, puA);
    readF(bbE, sB_b0k0, rB,  la32, puA);
    readF(a1,  sA_b0k0, rA1, la32, puA);
    stageA(1, 1, v);
    SB(); BAR(); SB();
    PRIO1(); mfma8(acc, a0, bbE, 0); PRIO0(); SB();
    BAR(); SB();
    readF(a0,  sA_b0k1, rA0, la32, puA);
    readF(bbO, sB_b0k1, rB,  la32, puA);
    stageB(1, 1, v);
    SB(); BAR(); SB();
    PRIO1(); mfma8(acc, a1, bbE, 1); PRIO0(); SB();
    BAR(); SB();
    readF(a1,  sA_b0k1, rA1, la32, puA);
    stageA(0, 0, u + 2);
    SB(); BAR(); SB();
    PRIO1(); mfma8(acc, a0, bbO, 0); PRIO0(); SB();
    VM6();
    BAR(); SB();
    readF(a0,  sA_b1k0, rA0, la32, puA);
    readF(bbE, sB_b1k0, rB,  la32, puA);
    stageB(0, 0, u + 2);
    SB(); BAR(); SB();
    PRIO1(); mfma8(acc, a1, bbO, 1); PRIO0(); SB();
    VM4();
    BAR(); SB();
    readF(a1,  sA_b1k0, rA1, la32, puA);
    stageA(0, 1, u + 2);
    SB(); BAR(); SB();
    PRIO1(); mfma8(acc, a0, bbE, 0); PRIO0(); SB();
    BAR(); SB();
    readF(a0,  sA_b1k1, rA0, la32, puA);
    readF(bbO, sB_b1k1, rB,  la32, puA);
    stageB(0, 1, u + 2);
    SB(); BAR(); SB();
    PRIO1(); mfma8(acc, a1, bbE, 1); PRIO0(); SB();
    BAR(); SB();
    readF(a1,  sA_b1k1, rA1, la32, puA);
    stageA(1, 0, v + 2);
    SB(); BAR(); SB();
    PRIO1(); mfma8(acc, a0, bbO, 0); PRIO0(); SB();
    BAR(); SB();
    stageB(1, 0, v + 2);
    SB(); BAR(); SB();
    PRIO1(); mfma8(acc, a1, bbO, 1); PRIO0(); SB();
    VM4();
    BAR(); SB();
  }

  const int seg = (int)(colBase >> 10);
  const size_t colSeg = colBase & 1023;
  void* Cout;
  if (EPI == 3)      Cout = (seg == 0) ? C0 : (seg == 1) ? C1 : C2;
  else if (EPI == 2) Cout = (seg == 0) ? C0 : C1;
  else               Cout = C0;

#pragma unroll
  for (int mi = 0; mi < 4; ++mi)
#pragma unroll
    for (int ni = 0; ni < 2; ++ni) {
      const int cn = wc * 64 + ni * 32 + la32;
      const float badd = (EPI == 1) ? bias[colBase + cn] : 0.0f;
      const size_t col = colSeg + cn;
#pragma unroll
      for (int r = 0; r < 16; ++r) {
        const size_t row = rowBase + wr * 128 + mi * 32 + (r & 3) + 8 * (r >> 2) + 4 * g2;
        const float v = acc[mi][ni][r] + badd;
        if (EPI == 2) ((float*)Cout)[row * (size_t)ldc + col] = v;
        else          ((u16*)Cout)[row * (size_t)ldc + col] = f2bf(v);
      }
    }
}

// ---------------- LayerNorm (in-place on bf16 rows) ----------------

__global__ __launch_bounds__(256) void ln_kernel(u16* __restrict__ xc,
    const float* __restrict__ gamma, const float* __restrict__ beta)
{
  const size_t row = blockIdx.x;
  u16* p = xc + row * D_DIM;
  const int tid = threadIdx.x;
  const int c = tid * 4;
  const uint2 raw = *(const uint2*)(p + c);
  const float v0 = bf2f((u16)(raw.x & 0xffff)), v1 = bf2f((u16)(raw.x >> 16));
  const float v2 = bf2f((u16)(raw.y & 0xffff)), v3 = bf2f((u16)(raw.y >> 16));
  float s = v0 + v1 + v2 + v3;
  float q = v0 * v0 + v1 * v1 + v2 * v2 + v3 * v3;
#pragma unroll
  for (int o = 32; o > 0; o >>= 1) { s += __shfl_xor(s, o); q += __shfl_xor(q, o); }
  __shared__ float red[8];
  if ((tid & 63) == 0) { red[(tid >> 6) * 2] = s; red[(tid >> 6) * 2 + 1] = q; }
  __syncthreads();
  s = red[0] + red[2] + red[4] + red[6];
  q = red[1] + red[3] + red[5] + red[7];
  const float mu = s * (1.0f / D_DIM);
  const float var = q * (1.0f / D_DIM) - mu * mu;
  const float rstd = 1.0f / sqrtf(var + 1e-5f);
  const float y0 = (v0 - mu) * rstd * gamma[c] + beta[c];
  const float y1 = (v1 - mu) * rstd * gamma[c + 1] + beta[c + 1];
  const float y2 = (v2 - mu) * rstd * gamma[c + 2] + beta[c + 2];
  const float y3 = (v3 - mu) * rstd * gamma[c + 3] + beta[c + 3];
  const uint32_t o0 = (uint32_t)f2bf(y0) | ((uint32_t)f2bf(y1) << 16);
  const uint32_t o1 = (uint32_t)f2bf(y2) | ((uint32_t)f2bf(y3) << 16);
  *(uint2*)(p + c) = make_uint2(o0, o1);
}

// ---------------- gate[row,h] = sigmoid(q.k / sqrt(DH)) ----------------

__global__ __launch_bounds__(256) void gate_kernel(
    const u16* __restrict__ Q, const u16* __restrict__ Kb, float* __restrict__ gate)
{
  const int gw = blockIdx.x * 4 + (threadIdx.x >> 6);
  const int lane = threadIdx.x & 63;
  const size_t row = (size_t)(gw >> 3);
  const int h = gw & 7;
  const size_t off = row * D_DIM + h * DH_DIM + lane * 2;
  const uint32_t qr = *(const uint32_t*)(Q + off);
  const uint32_t kr = *(const uint32_t*)(Kb + off);
  float d = bf2f((u16)(qr & 0xffff)) * bf2f((u16)(kr & 0xffff))
          + bf2f((u16)(qr >> 16))    * bf2f((u16)(kr >> 16));
#pragma unroll
  for (int o = 32; o > 0; o >>= 1) d += __shfl_xor(d, o);
  if (lane == 0) {
    const float x = d * 0.08838834764831845f;
    gate[gw] = 1.0f / (1.0f + expf(-x));
  }
}

// ---------------- chunked EMA scan: 8 chunks of 64 timesteps ----------------

__global__ __launch_bounds__(256) void scan1_kernel(
    const u16* __restrict__ vb, const float* __restrict__ log_alpha,
    float* __restrict__ carry)
{
  const int j  = blockIdx.x >> 7;
  const int th = (blockIdx.x & 127) * 256 + threadIdx.x;
  const int gid = th * 2;
  const int b = gid >> 10;
  const int c = gid & 1023;
  const int h = c >> 7;
  const float alpha = 1.0f / (1.0f + expf(-log_alpha[h]));
  const float oma = 1.0f - alpha;
  const u16* vp = vb + ((size_t)(4096 * j + b)) * 1024 + c;
  float s0 = 0.f, s1 = 0.f;
#pragma unroll 8
  for (int i = 0; i < 64; ++i) {
    const uint32_t uv = *(const uint32_t*)(vp + (size_t)i * 65536);
    s0 = alpha * bf2f((u16)(uv & 0xffff)) + oma * s0;
    s1 = alpha * bf2f((u16)(uv >> 16))    + oma * s1;
  }
  *(float2*)(carry + (size_t)j * 65536 + gid) = make_float2(s0, s1);
}

__global__ __launch_bounds__(256) void scan2_kernel(
    const u16* __restrict__ vb, const float* __restrict__ gate,
    const float* __restrict__ vstate, const float* __restrict__ log_alpha,
    const float* __restrict__ carry,
    u16* __restrict__ ret, float* __restrict__ fstate)
{
  const int j  = blockIdx.x >> 7;
  const int th = (blockIdx.x & 127) * 256 + threadIdx.x;
  const int gid = th * 2;
  const int b = gid >> 10;
  const int c = gid & 1023;
  const int h = c >> 7;
  const float alpha = 1.0f / (1.0f + expf(-log_alpha[h]));
  const float oma = 1.0f - alpha;
  float o64 = oma;
#pragma unroll
  for (int q = 0; q < 6; ++q) o64 *= o64;
  float s0 = vstate[gid], s1 = vstate[gid + 1];
  for (int i = 0; i < j; ++i) {
    const float2 L = *(const float2*)(carry + (size_t)i * 65536 + gid);
    s0 = L.x + o64 * s0;
    s1 = L.y + o64 * s1;
  }
  const u16* vp = vb + ((size_t)(4096 * j + b)) * 1024 + c;
  u16* rp = ret + ((size_t)(4096 * j + b)) * 1024 + c;
  const float* gp = gate + (size_t)(4096 * j + b) * H_DIM + h;
#pragma unroll 4
  for (int i = 0; i < 64; ++i) {
    const uint32_t uv = *(const uint32_t*)(vp + (size_t)i * 65536);
    const float g = gp[(size_t)i * 512];
    s0 = alpha * bf2f((u16)(uv & 0xffff)) + oma * s0;
    s1 = alpha * bf2f((u16)(uv >> 16))    + oma * s1;
    const uint32_t o = (uint32_t)f2bf(g * s0) | ((uint32_t)f2bf(g * s1) << 16);
    *(uint32_t*)(rp + (size_t)i * 65536) = o;
  }
  if (j == 7) { fstate[gid] = s0; fstate[gid + 1] = s1; }
}

// ---------------- launch ----------------

extern "C" void kernel_launch(void* const* d_in, const int* in_sizes, int n_in,
                              void* d_out, int out_size, void* d_ws, size_t ws_size,
                              hipStream_t stream) {
  const float* x_real      = (const float*)d_in[0];
  const float* x_imag      = (const float*)d_in[1];
  const float* value_state = (const float*)d_in[2];
  const float* Wr_in  = (const float*)d_in[4];
  const float* Wi_in  = (const float*)d_in[5];
  const float* br_in  = (const float*)d_in[6];
  const float* bi_in  = (const float*)d_in[7];
  const float* ln_g   = (const float*)d_in[8];
  const float* ln_b   = (const float*)d_in[9];
  const float* W_qkv  = (const float*)d_in[10];
  const float* log_alpha = (const float*)d_in[11];
  const float* Wr_out = (const float*)d_in[12];
  const float* Wi_out = (const float*)d_in[13];

  float* out_real = (float*)d_out;
  float* out_imag = out_real + (size_t)MROWS * D_DIM;
  float* fstate   = out_imag + (size_t)MROWS * D_DIM;

  u16* R0a = (u16*)d_out;                                        // Q (gemm3 output)
  u16* xc  = (u16*)((char*)d_out + (size_t)MROWS * D_DIM * 2);   // proj out, LN'd
  u16* Vb  = (u16*)out_imag;                                     // V

  char* ws = (char*)d_ws;
  size_t off = 0;
  auto alloc = [&](size_t bytes) { void* p = ws + off; off += (bytes + 255) & ~(size_t)255; return p; };
  u16*   Wc    = (u16*)alloc((size_t)1024 * 2048 * 2);
  u16*   Wqkvb = (u16*)alloc((size_t)3072 * 1024 * 2);
  u16*   Wob   = (u16*)alloc((size_t)2048 * 1024 * 2);
  float* bc    = (float*)alloc((size_t)D_DIM * 4);
  u16*   R0b   = (u16*)alloc((size_t)MROWS * D_DIM * 2); // K -> retrieved
  float* gate  = (float*)alloc((size_t)MROWS * H_DIM * 4);
  float* carry = (float*)alloc((size_t)8 * B_DIM * D_DIM * 4);

  const int LDSB = 131072;
  hipFuncSetAttribute((const void*)gemm_f32a_kernel,  hipFuncAttributeMaxDynamicSharedMemorySize, LDSB);
  hipFuncSetAttribute((const void*)gemm256_kernel<2>, hipFuncAttributeMaxDynamicSharedMemorySize, LDSB);
  hipFuncSetAttribute((const void*)gemm256_kernel<3>, hipFuncAttributeMaxDynamicSharedMemorySize, LDSB);

  // weight prep only (x casts eliminated)
  prep_cast_kernel<<<10756, 256, 0, stream>>>(Wr_in, Wi_in, br_in, bi_in, W_qkv, Wr_out, Wi_out,
                                              Wc, bc, Wqkvb, Wob);

  // input proj straight from f32 x: xc_pre = [xr|xi] @ Wc^T + bc (8-phase, A reg-staged)
  gemm_f32a_kernel<<<dim3(128 * 4), 512, LDSB, stream>>>(
      x_real, x_imag, 1024, 1024, Wc, 2048, bc, xc, 1024, 2048, 4);
  // LayerNorm in place
  ln_kernel<<<MROWS, 256, 0, stream>>>(xc, ln_g, ln_b);
  // QKV in ONE GEMM (N=3072): Q -> R0a, K -> R0b, V -> Vb
  gemm256_kernel<3><<<dim3(128 * 12), 512, LDSB, stream>>>(
      xc, xc, 1024, 1024, Wqkvb, 1024, nullptr, R0a, R0b, Vb, 1024, 1024, 12);
  // gate from Q,K
  gate_kernel<<<(MROWS * H_DIM) / 4, 256, 0, stream>>>(R0a, R0b, gate);
  // chunked EMA scan
  scan1_kernel<<<1024, 256, 0, stream>>>(Vb, log_alpha, carry);
  scan2_kernel<<<1024, 256, 0, stream>>>(Vb, gate, value_state, log_alpha, carry, R0b, fstate);
  // output projections in ONE GEMM (N=2048, f32 out)
  gemm256_kernel<2><<<dim3(128 * 8), 512, LDSB, stream>>>(
      R0b, R0b, 1024, 1024, Wob, 1024, nullptr, out_real, out_imag, nullptr, 1024, 1024, 8);
}

// Round 15
// 701.476 us; speedup vs baseline: 1.1658x; 1.1658x over previous
//
#include <hip/hip_runtime.h>
#include <stdint.h>

#define T_DIM 512
#define B_DIM 64
#define D_DIM 1024
#define H_DIM 8
#define DH_DIM 128
#define MROWS (T_DIM * B_DIM)   // 32768 rows across all timesteps

typedef unsigned short u16;
typedef __attribute__((ext_vector_type(8))) __bf16 bf16x8;
typedef __attribute__((ext_vector_type(4))) float f32x4;
typedef __attribute__((ext_vector_type(16))) float f32x16;

__device__ __forceinline__ u16 f2bf(float f) {
  union { float f; uint32_t u; } v; v.f = f;
  uint32_t u = v.u;
  u += 0x7fffu + ((u >> 16) & 1u);   // RNE
  return (u16)(u >> 16);
}
__device__ __forceinline__ float bf2f(u16 h) {
  union { uint32_t u; float f; } v; v.u = ((uint32_t)h) << 16;
  return v.f;
}

__device__ __forceinline__ void gload16(const void* g, void* l) {
  __builtin_amdgcn_global_load_lds(
      (const __attribute__((address_space(1))) uint32_t*)g,
      (__attribute__((address_space(3))) uint32_t*)l, 16, 0, 0);
}

#define SB()  __builtin_amdgcn_sched_barrier(0)
#define BAR() __builtin_amdgcn_s_barrier()
#define VM4() asm volatile("s_waitcnt vmcnt(4)" ::: "memory")
#define VM6() asm volatile("s_waitcnt vmcnt(6)" ::: "memory")
#define VM12() asm volatile("s_waitcnt vmcnt(12)" ::: "memory")
#define LGK0() asm volatile("s_waitcnt lgkmcnt(0)" ::: "memory")
#define PRIO1() __builtin_amdgcn_s_setprio(1)
#define PRIO0() __builtin_amdgcn_s_setprio(0)

// ---------------- weight prep (x casts ELIMINATED — gemm1 reads f32 x directly) ----------------

__device__ __forceinline__ void cast8(const float* __restrict__ in, u16* __restrict__ out, size_t i) {
  const float4 a = ((const float4*)in)[i * 2];
  const float4 b = ((const float4*)in)[i * 2 + 1];
  union { u16 h[8]; uint4 u; } o;
  o.h[0] = f2bf(a.x); o.h[1] = f2bf(a.y); o.h[2] = f2bf(a.z); o.h[3] = f2bf(a.w);
  o.h[4] = f2bf(b.x); o.h[5] = f2bf(b.y); o.h[6] = f2bf(b.z); o.h[7] = f2bf(b.w);
  ((uint4*)out)[i] = o.u;
}

// blocks: [0,8192) Wc | [8192,9728) Wqkv | [9728,10240) Wr_out | [10240,10752) Wi_out | [10752,10756) bc
__global__ void prep_cast_kernel(const float* __restrict__ Wr, const float* __restrict__ Wi,
                                 const float* __restrict__ br, const float* __restrict__ bi,
                                 const float* __restrict__ Wqkv,
                                 const float* __restrict__ Wro, const float* __restrict__ Wio,
                                 u16* __restrict__ Wc, float* __restrict__ bc,
                                 u16* __restrict__ Wqkvb, u16* __restrict__ Wob) {
  const int blk = blockIdx.x;
  if (blk < 8192) {                      // Wc[n][k]: (1024,2048) bf16
    const int idx = blk * 256 + threadIdx.x;
    const int n = idx >> 11;
    const int k = idx & 2047;
    const int kk = k & 1023;
    const float a = Wr[n * 1024 + kk], b = Wi[n * 1024 + kk];
    Wc[idx] = f2bf(k < 1024 ? a + b : a - b);
  } else if (blk < 9728) {
    cast8(Wqkv, Wqkvb, (size_t)(blk - 8192) * 256 + threadIdx.x);
  } else if (blk < 10240) {
    cast8(Wro, Wob, (size_t)(blk - 9728) * 256 + threadIdx.x);
  } else if (blk < 10752) {
    cast8(Wio, Wob + (size_t)1024 * 1024, (size_t)(blk - 10240) * 256 + threadIdx.x);
  } else {
    const int i = (blk - 10752) * 256 + threadIdx.x;
    if (i < D_DIM) bc[i] = br[i] + bi[i];
  }
}

// ---------------- shared GEMM pieces ----------------

__device__ __forceinline__ void readF(bf16x8 (&d)[2][2], const u16* s, int rowoff, int la32, int puA) {
#pragma unroll
  for (int mf = 0; mf < 2; ++mf)
#pragma unroll
    for (int kk = 0; kk < 2; ++kk)
      d[mf][kk] = *(const bf16x8*)(s + (rowoff + mf * 32 + la32) * 32 + (puA ^ (kk << 4)));
}

__device__ __forceinline__ void mfma8(f32x16 (&acc)[4][2], const bf16x8 (&a)[2][2],
                                      const bf16x8 (&b)[2][2], int QM) {
#pragma unroll
  for (int kk = 0; kk < 2; ++kk)
#pragma unroll
    for (int mf = 0; mf < 2; ++mf)
#pragma unroll
      for (int nf = 0; nf < 2; ++nf)
        acc[QM * 2 + mf][nf] =
            __builtin_amdgcn_mfma_f32_32x32x16_bf16(a[mf][kk], b[nf][kk], acc[QM * 2 + mf][nf], 0, 0, 0);
}

// ------- gemm1 variant: A from f32 GLOBAL via reg-staging (kills the x-cast pass) -------
// 256x256 tile, 8 waves, BK=64, 2-buffer 1-deep pipeline (round-3 shape, proven-simple).
// A: 8 x dwordx4 f32 loads -> f2bf (same RNE as cast kernel -> bit-identical values) ->
//    4 x ds_write_b128 at the SAME LDS addresses gload16 used (swizzle/read side unchanged).
// B: 4 x gload16 from bf16 Wc (unchanged).
// vmem/iter = 12 (8 A + 4 B). VM12 at iter end drains exactly B(t+1) while tile t+2 flies.
// cvt's compiler reg-dep wait covers A (issued one full tile earlier -> latency covered).
// LGK0 publishes ds_writes before each barrier.
// Tail: clamp t to 0 (dummy traffic to never-again-read regions; keeps vmcnt queue exact).
__global__ __launch_bounds__(512, 2) void gemm_f32a_kernel(
    const float* __restrict__ A0f, const float* __restrict__ A1f, int kSplit, int lda,
    const u16* __restrict__ Bw, int ldb,
    const float* __restrict__ bias,
    u16* __restrict__ C0, int ldc, int K, int nColBlk)
{
  extern __shared__ u16 lds[];   // 2 x (A 16KB | B 16KB) = 64 KB used (128 KB reserved)
  const int tid  = threadIdx.x;
  const int lane = tid & 63;
  const int w    = tid >> 6;
  const int wr   = w >> 2;
  const int wc   = w & 3;

  const int bid   = blockIdx.x;
  const int xcd   = bid & 7;
  const int local = bid >> 3;
  const int rowL  = local / nColBlk;
  const int colB  = local - rowL * nColBlk;
  const size_t rowBase = (size_t)(xcd * 16 + rowL) * 256;
  const size_t colBase = (size_t)colB * 256;

  f32x16 acc[4][2];
#pragma unroll
  for (int i = 0; i < 4; ++i)
#pragma unroll
    for (int j = 0; j < 2; ++j)
#pragma unroll
      for (int e = 0; e < 16; ++e) acc[i][j][e] = 0.f;

  const int NT = K >> 6;
  const int la32 = lane & 31;
  const int g2   = lane >> 5;
  const int f    = (la32 & 3) ^ ((la32 >> 2) & 3);
  const int puA  = ((g2 ^ f) << 3);

  float4 ar[8];   // one tile's A elems: [ks*4 + i2*2 + j]

  auto aload = [&](int t) {
    if (t >= NT) t = 0;
    const int kb = t * 64;
    const float* Af; int kc;
    if (kb < kSplit) { Af = A0f; kc = kb; } else { Af = A1f; kc = kb - kSplit; }
#pragma unroll
    for (int ks = 0; ks < 2; ++ks)
#pragma unroll
      for (int i2 = 0; i2 < 2; ++i2) {
        const int l = i2 * 512 + tid, r = l >> 2, p = l & 3;
        const int lu = p ^ (r & 3) ^ ((r >> 2) & 3);
        const float* g = Af + (rowBase + r) * (size_t)lda + kc + ks * 32 + lu * 8;
        ar[ks * 4 + i2 * 2 + 0] = *(const float4*)g;
        ar[ks * 4 + i2 * 2 + 1] = *(const float4*)(g + 4);
      }
  };
  auto cwrite = [&](int buf) {   // cvt + ds_write (reads ar -> compiler waits the A loads)
#pragma unroll
    for (int ks = 0; ks < 2; ++ks)
#pragma unroll
      for (int i2 = 0; i2 < 2; ++i2) {
        const int l = i2 * 512 + tid;
        const float4 x0 = ar[ks * 4 + i2 * 2 + 0];
        const float4 x1 = ar[ks * 4 + i2 * 2 + 1];
        union { u16 h[8]; uint4 u; } o;
        o.h[0] = f2bf(x0.x); o.h[1] = f2bf(x0.y); o.h[2] = f2bf(x0.z); o.h[3] = f2bf(x0.w);
        o.h[4] = f2bf(x1.x); o.h[5] = f2bf(x1.y); o.h[6] = f2bf(x1.z); o.h[7] = f2bf(x1.w);
        *(uint4*)(lds + buf * 32768 + ks * 8192 + (size_t)l * 8) = o.u;
      }
  };
  auto bgload = [&](int buf, int t) {
    if (t >= NT) t = 0;
    const int kb = t * 64;
#pragma unroll
    for (int ks = 0; ks < 2; ++ks)
#pragma unroll
      for (int i2 = 0; i2 < 2; ++i2) {
        const int l = i2 * 512 + tid, r = l >> 2, p = l & 3;
        const int lu = p ^ (r & 3) ^ ((r >> 2) & 3);
        gload16(Bw + (colBase + r) * (size_t)ldb + kb + ks * 32 + lu * 8,
                lds + buf * 32768 + 16384 + ks * 8192 + (size_t)l * 8);
      }
  };

  const int rA0 = wr * 128;
  const int rA1 = wr * 128 + 64;
  const int rB  = wc * 64;

  // prologue: tile0 (A regs + B gload + cvt_write), tile1 issued; drain B(t0)
  aload(0);
  bgload(0, 0);
  cwrite(0);                 // waits A(t0) [leaves B(t0) flying]
  aload(1);
  bgload(1, 1);
  SB(); VM12(); LGK0(); BAR(); SB();   // B(t0) done; A(t1)8+B(t1)4 = 12 in flight

  bf16x8 a0[2][2], a1[2][2], bb[2][2];
  for (int t = 0; t < NT; ++t) {
    const int cur = t & 1, o = cur ^ 1;
    const u16* sA = lds + cur * 32768;
    const u16* sBt = lds + cur * 32768 + 16384;
    // compute tile t (same per-acc k-order as the proven 8-phase kernel: ks0 kk01, ks1 kk01)
    readF(a0, sA, rA0, la32, puA);
    readF(a1, sA, rA1, la32, puA);
    readF(bb, sBt, rB, la32, puA);
    PRIO1(); mfma8(acc, a0, bb, 0); mfma8(acc, a1, bb, 1); PRIO0();
    readF(a0, sA + 8192, rA0, la32, puA);
    readF(a1, sA + 8192, rA1, la32, puA);
    readF(bb, sBt + 8192, rB, la32, puA);
    PRIO1(); mfma8(acc, a0, bb, 0); mfma8(acc, a1, bb, 1); PRIO0();
    SB(); BAR(); SB();
    // stage ahead: A(t+1) regs -> b[o].A ; issue A(t+2), B(t+2 -> b[cur].B)
    cwrite(o);               // ar holds A(t+1); waits its loads (leaves B(t+1) flying)
    aload(t + 2);            // reg WAR after cwrite's reads (in-wave order)
    bgload(cur, t + 2);      // b[cur].B was read above; barrier passed
    SB(); VM12(); LGK0(); BAR(); SB();   // drains B(t+1); A(t+2)+B(t+2)=12 fly
  }

  // epilogue: bf16 out + bias (EPI==1 semantics), single C0
#pragma unroll
  for (int mi = 0; mi < 4; ++mi)
#pragma unroll
    for (int ni = 0; ni < 2; ++ni) {
      const int cn = wc * 64 + ni * 32 + la32;
      const float badd = bias[colBase + cn];
      const size_t col = colBase + cn;
#pragma unroll
      for (int r = 0; r < 16; ++r) {
        const size_t row = rowBase + wr * 128 + mi * 32 + (r & 3) + 8 * (r >> 2) + 4 * g2;
        C0[row * (size_t)ldc + col] = f2bf(acc[mi][ni][r] + badd);
      }
    }
}

// ------- 256x256 8-phase bf16 MFMA GEMM (32x32x16), one-phase-ahead register pipeline -------
// Round-9 verified configuration (absmax bit-exact across rounds, 0 bank conflicts) — UNTOUCHED.

template <int EPI>
__global__ __launch_bounds__(512, 2) void gemm256_kernel(
    const u16* __restrict__ A0, const u16* __restrict__ A1, int kSplit, int lda,
    const u16* __restrict__ Bw, int ldb,
    const float* __restrict__ bias,
    void* __restrict__ C0, void* __restrict__ C1, void* __restrict__ C2,
    int ldc, int K, int nColBlk)
{
  extern __shared__ u16 lds[];   // 65536 u16 = 128 KB
  const int tid  = threadIdx.x;
  const int lane = tid & 63;
  const int w    = tid >> 6;
  const int wr   = w >> 2;
  const int wc   = w & 3;

  const int bid   = blockIdx.x;
  const int xcd   = bid & 7;
  const int local = bid >> 3;
  const int rowL  = local / nColBlk;
  const int colB  = local - rowL * nColBlk;
  const size_t rowBase = (size_t)(xcd * 16 + rowL) * 256;
  const size_t colBase = (size_t)colB * 256;

  f32x16 acc[4][2];
#pragma unroll
  for (int i = 0; i < 4; ++i)
#pragma unroll
    for (int j = 0; j < 2; ++j)
#pragma unroll
      for (int e = 0; e < 16; ++e) acc[i][j][e] = 0.f;

  const int NT = K >> 6;
  const int la32 = lane & 31;
  const int g2   = lane >> 5;
  const int f    = (la32 & 3) ^ ((la32 >> 2) & 3);
  const int puA  = ((g2 ^ f) << 3);

  auto stageA = [&](int buf, int ks, int t) {
    if (t >= NT) t = 0;   // dummy stage keeps vmcnt queue exact in the tail
    const int kb = t * 64;
    const u16* Ab; int kc;
    if (kb < kSplit) { Ab = A0; kc = kb; } else { Ab = A1; kc = kb - kSplit; }
    u16* dst = lds + buf * 32768 + ks * 8192;
#pragma unroll
    for (int i2 = 0; i2 < 2; ++i2) {
      const int l = i2 * 512 + tid, r = l >> 2, p = l & 3;
      const int lu = p ^ (r & 3) ^ ((r >> 2) & 3);
      gload16(Ab + (rowBase + r) * (size_t)lda + kc + ks * 32 + lu * 8, dst + l * 8);
    }
  };
  auto stageB = [&](int buf, int ks, int t) {
    if (t >= NT) t = 0;
    const int kb = t * 64;
    u16* dst = lds + buf * 32768 + 16384 + ks * 8192;
#pragma unroll
    for (int i2 = 0; i2 < 2; ++i2) {
      const int l = i2 * 512 + tid, r = l >> 2, p = l & 3;
      const int lu = p ^ (r & 3) ^ ((r >> 2) & 3);
      gload16(Bw + (colBase + r) * (size_t)ldb + kb + ks * 32 + lu * 8, dst + l * 8);
    }
  };

  const u16* sA_b0k0 = lds;
  const u16* sA_b0k1 = lds + 8192;
  const u16* sB_b0k0 = lds + 16384;
  const u16* sB_b0k1 = lds + 16384 + 8192;
  const u16* sA_b1k0 = lds + 32768;
  const u16* sA_b1k1 = lds + 32768 + 8192;
  const u16* sB_b1k0 = lds + 32768 + 16384;
  const u16* sB_b1k1 = lds + 32768 + 16384 + 8192;
  const int rA0 = wr * 128;
  const int rA1 = wr * 128 + 64;
  const int rB  = wc * 64;

  stageA(0, 0, 0); stageB(0, 0, 0); stageA(0, 1, 0); stageB(0, 1, 0);
  stageA(1, 0, 1); stageB(1, 0, 1);
  VM4();
  SB(); BAR(); SB();

  bf16x8 a0[2][2], a1[2][2], bbE[2][2], bbO[2][2];
  const int NIT = NT >> 1;
  for (int i = 0; i < NIT; ++i) {
    const int u = 2 * i, v = 2 * i + 1;
    readF(a0,  sA_b0k0, rA0, la32, puA);
    readF(bbE, sB_b0k0, rB,  la32, puA);
    readF(a1,  sA_b0k0, rA1, la32, puA);
    stageA(1, 1, v);
    SB(); BAR(); SB();
    PRIO1(); mfma8(acc, a0, bbE, 0); PRIO0(); SB();
    BAR(); SB();
    readF(a0,  sA_b0k1, rA0, la32, puA);
    readF(bbO, sB_b0k1, rB,  la32, puA);
    stageB(1, 1, v);
    SB(); BAR(); SB();
    PRIO1(); mfma8(acc, a1, bbE, 1); PRIO0(); SB();
    BAR(); SB();
    readF(a1,  sA_b0k1, rA1, la32, puA);
    stageA(0, 0, u + 2);
    SB(); BAR(); SB();
    PRIO1(); mfma8(acc, a0, bbO, 0); PRIO0(); SB();
    VM6();
    BAR(); SB();
    readF(a0,  sA_b1k0, rA0, la32, puA);
    readF(bbE, sB_b1k0, rB,  la32, puA);
    stageB(0, 0, u + 2);
    SB(); BAR(); SB();
    PRIO1(); mfma8(acc, a1, bbO, 1); PRIO0(); SB();
    VM4();
    BAR(); SB();
    readF(a1,  sA_b1k0, rA1, la32, puA);
    stageA(0, 1, u + 2);
    SB(); BAR(); SB();
    PRIO1(); mfma8(acc, a0, bbE, 0); PRIO0(); SB();
    BAR(); SB();
    readF(a0,  sA_b1k1, rA0, la32, puA);
    readF(bbO, sB_b1k1, rB,  la32, puA);
    stageB(0, 1, u + 2);
    SB(); BAR(); SB();
    PRIO1(); mfma8(acc, a1, bbE, 1); PRIO0(); SB();
    BAR(); SB();
    readF(a1,  sA_b1k1, rA1, la32, puA);
    stageA(1, 0, v + 2);
    SB(); BAR(); SB();
    PRIO1(); mfma8(acc, a0, bbO, 0); PRIO0(); SB();
    BAR(); SB();
    stageB(1, 0, v + 2);
    SB(); BAR(); SB();
    PRIO1(); mfma8(acc, a1, bbO, 1); PRIO0(); SB();
    VM4();
    BAR(); SB();
  }

  const int seg = (int)(colBase >> 10);
  const size_t colSeg = colBase & 1023;
  void* Cout;
  if (EPI == 3)      Cout = (seg == 0) ? C0 : (seg == 1) ? C1 : C2;
  else if (EPI == 2) Cout = (seg == 0) ? C0 : C1;
  else               Cout = C0;

#pragma unroll
  for (int mi = 0; mi < 4; ++mi)
#pragma unroll
    for (int ni = 0; ni < 2; ++ni) {
      const int cn = wc * 64 + ni * 32 + la32;
      const float badd = (EPI == 1) ? bias[colBase + cn] : 0.0f;
      const size_t col = colSeg + cn;
#pragma unroll
      for (int r = 0; r < 16; ++r) {
        const size_t row = rowBase + wr * 128 + mi * 32 + (r & 3) + 8 * (r >> 2) + 4 * g2;
        const float v = acc[mi][ni][r] + badd;
        if (EPI == 2) ((float*)Cout)[row * (size_t)ldc + col] = v;
        else          ((u16*)Cout)[row * (size_t)ldc + col] = f2bf(v);
      }
    }
}

// ---------------- LayerNorm (in-place on bf16 rows) ----------------

__global__ __launch_bounds__(256) void ln_kernel(u16* __restrict__ xc,
    const float* __restrict__ gamma, const float* __restrict__ beta)
{
  const size_t row = blockIdx.x;
  u16* p = xc + row * D_DIM;
  const int tid = threadIdx.x;
  const int c = tid * 4;
  const uint2 raw = *(const uint2*)(p + c);
  const float v0 = bf2f((u16)(raw.x & 0xffff)), v1 = bf2f((u16)(raw.x >> 16));
  const float v2 = bf2f((u16)(raw.y & 0xffff)), v3 = bf2f((u16)(raw.y >> 16));
  float s = v0 + v1 + v2 + v3;
  float q = v0 * v0 + v1 * v1 + v2 * v2 + v3 * v3;
#pragma unroll
  for (int o = 32; o > 0; o >>= 1) { s += __shfl_xor(s, o); q += __shfl_xor(q, o); }
  __shared__ float red[8];
  if ((tid & 63) == 0) { red[(tid >> 6) * 2] = s; red[(tid >> 6) * 2 + 1] = q; }
  __syncthreads();
  s = red[0] + red[2] + red[4] + red[6];
  q = red[1] + red[3] + red[5] + red[7];
  const float mu = s * (1.0f / D_DIM);
  const float var = q * (1.0f / D_DIM) - mu * mu;
  const float rstd = 1.0f / sqrtf(var + 1e-5f);
  const float y0 = (v0 - mu) * rstd * gamma[c] + beta[c];
  const float y1 = (v1 - mu) * rstd * gamma[c + 1] + beta[c + 1];
  const float y2 = (v2 - mu) * rstd * gamma[c + 2] + beta[c + 2];
  const float y3 = (v3 - mu) * rstd * gamma[c + 3] + beta[c + 3];
  const uint32_t o0 = (uint32_t)f2bf(y0) | ((uint32_t)f2bf(y1) << 16);
  const uint32_t o1 = (uint32_t)f2bf(y2) | ((uint32_t)f2bf(y3) << 16);
  *(uint2*)(p + c) = make_uint2(o0, o1);
}

// ---------------- gate[row,h] = sigmoid(q.k / sqrt(DH)) ----------------

__global__ __launch_bounds__(256) void gate_kernel(
    const u16* __restrict__ Q, const u16* __restrict__ Kb, float* __restrict__ gate)
{
  const int gw = blockIdx.x * 4 + (threadIdx.x >> 6);
  const int lane = threadIdx.x & 63;
  const size_t row = (size_t)(gw >> 3);
  const int h = gw & 7;
  const size_t off = row * D_DIM + h * DH_DIM + lane * 2;
  const uint32_t qr = *(const uint32_t*)(Q + off);
  const uint32_t kr = *(const uint32_t*)(Kb + off);
  float d = bf2f((u16)(qr & 0xffff)) * bf2f((u16)(kr & 0xffff))
          + bf2f((u16)(qr >> 16))    * bf2f((u16)(kr >> 16));
#pragma unroll
  for (int o = 32; o > 0; o >>= 1) d += __shfl_xor(d, o);
  if (lane == 0) {
    const float x = d * 0.08838834764831845f;
    gate[gw] = 1.0f / (1.0f + expf(-x));
  }
}

// ---------------- chunked EMA scan: 8 chunks of 64 timesteps ----------------

__global__ __launch_bounds__(256) void scan1_kernel(
    const u16* __restrict__ vb, const float* __restrict__ log_alpha,
    float* __restrict__ carry)
{
  const int j  = blockIdx.x >> 7;
  const int th = (blockIdx.x & 127) * 256 + threadIdx.x;
  const int gid = th * 2;
  const int b = gid >> 10;
  const int c = gid & 1023;
  const int h = c >> 7;
  const float alpha = 1.0f / (1.0f + expf(-log_alpha[h]));
  const float oma = 1.0f - alpha;
  const u16* vp = vb + ((size_t)(4096 * j + b)) * 1024 + c;
  float s0 = 0.f, s1 = 0.f;
#pragma unroll 8
  for (int i = 0; i < 64; ++i) {
    const uint32_t uv = *(const uint32_t*)(vp + (size_t)i * 65536);
    s0 = alpha * bf2f((u16)(uv & 0xffff)) + oma * s0;
    s1 = alpha * bf2f((u16)(uv >> 16))    + oma * s1;
  }
  *(float2*)(carry + (size_t)j * 65536 + gid) = make_float2(s0, s1);
}

__global__ __launch_bounds__(256) void scan2_kernel(
    const u16* __restrict__ vb, const float* __restrict__ gate,
    const float* __restrict__ vstate, const float* __restrict__ log_alpha,
    const float* __restrict__ carry,
    u16* __restrict__ ret, float* __restrict__ fstate)
{
  const int j  = blockIdx.x >> 7;
  const int th = (blockIdx.x & 127) * 256 + threadIdx.x;
  const int gid = th * 2;
  const int b = gid >> 10;
  const int c = gid & 1023;
  const int h = c >> 7;
  const float alpha = 1.0f / (1.0f + expf(-log_alpha[h]));
  const float oma = 1.0f - alpha;
  float o64 = oma;
#pragma unroll
  for (int q = 0; q < 6; ++q) o64 *= o64;
  float s0 = vstate[gid], s1 = vstate[gid + 1];
  for (int i = 0; i < j; ++i) {
    const float2 L = *(const float2*)(carry + (size_t)i * 65536 + gid);
    s0 = L.x + o64 * s0;
    s1 = L.y + o64 * s1;
  }
  const u16* vp = vb + ((size_t)(4096 * j + b)) * 1024 + c;
  u16* rp = ret + ((size_t)(4096 * j + b)) * 1024 + c;
  const float* gp = gate + (size_t)(4096 * j + b) * H_DIM + h;
#pragma unroll 4
  for (int i = 0; i < 64; ++i) {
    const uint32_t uv = *(const uint32_t*)(vp + (size_t)i * 65536);
    const float g = gp[(size_t)i * 512];
    s0 = alpha * bf2f((u16)(uv & 0xffff)) + oma * s0;
    s1 = alpha * bf2f((u16)(uv >> 16))    + oma * s1;
    const uint32_t o = (uint32_t)f2bf(g * s0) | ((uint32_t)f2bf(g * s1) << 16);
    *(uint32_t*)(rp + (size_t)i * 65536) = o;
  }
  if (j == 7) { fstate[gid] = s0; fstate[gid + 1] = s1; }
}

// ---------------- launch ----------------

extern "C" void kernel_launch(void* const* d_in, const int* in_sizes, int n_in,
                              void* d_out, int out_size, void* d_ws, size_t ws_size,
                              hipStream_t stream) {
  const float* x_real      = (const float*)d_in[0];
  const float* x_imag      = (const float*)d_in[1];
  const float* value_state = (const float*)d_in[2];
  const float* Wr_in  = (const float*)d_in[4];
  const float* Wi_in  = (const float*)d_in[5];
  const float* br_in  = (const float*)d_in[6];
  const float* bi_in  = (const float*)d_in[7];
  const float* ln_g   = (const float*)d_in[8];
  const float* ln_b   = (const float*)d_in[9];
  const float* W_qkv  = (const float*)d_in[10];
  const float* log_alpha = (const float*)d_in[11];
  const float* Wr_out = (const float*)d_in[12];
  const float* Wi_out = (const float*)d_in[13];

  float* out_real = (float*)d_out;
  float* out_imag = out_real + (size_t)MROWS * D_DIM;
  float* fstate   = out_imag + (size_t)MROWS * D_DIM;

  u16* R0a = (u16*)d_out;                                        // Q (gemm3 output)
  u16* xc  = (u16*)((char*)d_out + (size_t)MROWS * D_DIM * 2);   // proj out, LN'd
  u16* Vb  = (u16*)out_imag;                                     // V

  char* ws = (char*)d_ws;
  size_t off = 0;
  auto alloc = [&](size_t bytes) { void* p = ws + off; off += (bytes + 255) & ~(size_t)255; return p; };
  u16*   Wc    = (u16*)alloc((size_t)1024 * 2048 * 2);
  u16*   Wqkvb = (u16*)alloc((size_t)3072 * 1024 * 2);
  u16*   Wob   = (u16*)alloc((size_t)2048 * 1024 * 2);
  float* bc    = (float*)alloc((size_t)D_DIM * 4);
  u16*   R0b   = (u16*)alloc((size_t)MROWS * D_DIM * 2); // K -> retrieved
  float* gate  = (float*)alloc((size_t)MROWS * H_DIM * 4);
  float* carry = (float*)alloc((size_t)8 * B_DIM * D_DIM * 4);

  const int LDSB = 131072;
  hipFuncSetAttribute((const void*)gemm_f32a_kernel,  hipFuncAttributeMaxDynamicSharedMemorySize, LDSB);
  hipFuncSetAttribute((const void*)gemm256_kernel<2>, hipFuncAttributeMaxDynamicSharedMemorySize, LDSB);
  hipFuncSetAttribute((const void*)gemm256_kernel<3>, hipFuncAttributeMaxDynamicSharedMemorySize, LDSB);

  // weight prep only (x casts eliminated)
  prep_cast_kernel<<<10756, 256, 0, stream>>>(Wr_in, Wi_in, br_in, bi_in, W_qkv, Wr_out, Wi_out,
                                              Wc, bc, Wqkvb, Wob);

  // input proj straight from f32 x: xc_pre = [xr|xi] @ Wc^T + bc
  gemm_f32a_kernel<<<dim3(128 * 4), 512, LDSB, stream>>>(
      x_real, x_imag, 1024, 1024, Wc, 2048, bc, xc, 1024, 2048, 4);
  // LayerNorm in place
  ln_kernel<<<MROWS, 256, 0, stream>>>(xc, ln_g, ln_b);
  // QKV in ONE GEMM (N=3072): Q -> R0a, K -> R0b, V -> Vb
  gemm256_kernel<3><<<dim3(128 * 12), 512, LDSB, stream>>>(
      xc, xc, 1024, 1024, Wqkvb, 1024, nullptr, R0a, R0b, Vb, 1024, 1024, 12);
  // gate from Q,K
  gate_kernel<<<(MROWS * H_DIM) / 4, 256, 0, stream>>>(R0a, R0b, gate);
  // chunked EMA scan
  scan1_kernel<<<1024, 256, 0, stream>>>(Vb, log_alpha, carry);
  scan2_kernel<<<1024, 256, 0, stream>>>(Vb, gate, value_state, log_alpha, carry, R0b, fstate);
  // output projections in ONE GEMM (N=2048, f32 out)
  gemm256_kernel<2><<<dim3(128 * 8), 512, LDSB, stream>>>(
      R0b, R0b, 1024, 1024, Wob, 1024, nullptr, out_real, out_imag, nullptr, 1024, 1024, 8);
}

// Round 16
// 699.594 us; speedup vs baseline: 1.1689x; 1.0027x over previous
//
#include <hip/hip_runtime.h>
#include <stdint.h>

#define T_DIM 512
#define B_DIM 64
#define D_DIM 1024
#define H_DIM 8
#define DH_DIM 128
#define MROWS (T_DIM * B_DIM)   // 32768 rows across all timesteps

typedef unsigned short u16;
typedef __attribute__((ext_vector_type(8))) __bf16 bf16x8;
typedef __attribute__((ext_vector_type(4))) float f32x4;
typedef __attribute__((ext_vector_type(16))) float f32x16;

__device__ __forceinline__ u16 f2bf(float f) {
  union { float f; uint32_t u; } v; v.f = f;
  uint32_t u = v.u;
  u += 0x7fffu + ((u >> 16) & 1u);   // RNE
  return (u16)(u >> 16);
}
__device__ __forceinline__ float bf2f(u16 h) {
  union { uint32_t u; float f; } v; v.u = ((uint32_t)h) << 16;
  return v.f;
}

__device__ __forceinline__ void gload16(const void* g, void* l) {
  __builtin_amdgcn_global_load_lds(
      (const __attribute__((address_space(1))) uint32_t*)g,
      (__attribute__((address_space(3))) uint32_t*)l, 16, 0, 0);
}

#define SB()  __builtin_amdgcn_sched_barrier(0)
#define BAR() __builtin_amdgcn_s_barrier()
#define VM4() asm volatile("s_waitcnt vmcnt(4)" ::: "memory")
#define VM6() asm volatile("s_waitcnt vmcnt(6)" ::: "memory")
#define VM12() asm volatile("s_waitcnt vmcnt(12)" ::: "memory")
#define LGK0() asm volatile("s_waitcnt lgkmcnt(0)" ::: "memory")
#define PRIO1() __builtin_amdgcn_s_setprio(1)
#define PRIO0() __builtin_amdgcn_s_setprio(0)

// ---------------- weight prep (x casts eliminated — gemm1 reads f32 x directly) ----------------

__device__ __forceinline__ void cast8(const float* __restrict__ in, u16* __restrict__ out, size_t i) {
  const float4 a = ((const float4*)in)[i * 2];
  const float4 b = ((const float4*)in)[i * 2 + 1];
  union { u16 h[8]; uint4 u; } o;
  o.h[0] = f2bf(a.x); o.h[1] = f2bf(a.y); o.h[2] = f2bf(a.z); o.h[3] = f2bf(a.w);
  o.h[4] = f2bf(b.x); o.h[5] = f2bf(b.y); o.h[6] = f2bf(b.z); o.h[7] = f2bf(b.w);
  ((uint4*)out)[i] = o.u;
}

// blocks: [0,8192) Wc | [8192,9728) Wqkv | [9728,10240) Wr_out | [10240,10752) Wi_out | [10752,10756) bc
__global__ void prep_cast_kernel(const float* __restrict__ Wr, const float* __restrict__ Wi,
                                 const float* __restrict__ br, const float* __restrict__ bi,
                                 const float* __restrict__ Wqkv,
                                 const float* __restrict__ Wro, const float* __restrict__ Wio,
                                 u16* __restrict__ Wc, float* __restrict__ bc,
                                 u16* __restrict__ Wqkvb, u16* __restrict__ Wob) {
  const int blk = blockIdx.x;
  if (blk < 8192) {                      // Wc[n][k]: (1024,2048) bf16
    const int idx = blk * 256 + threadIdx.x;
    const int n = idx >> 11;
    const int k = idx & 2047;
    const int kk = k & 1023;
    const float a = Wr[n * 1024 + kk], b = Wi[n * 1024 + kk];
    Wc[idx] = f2bf(k < 1024 ? a + b : a - b);
  } else if (blk < 9728) {
    cast8(Wqkv, Wqkvb, (size_t)(blk - 8192) * 256 + threadIdx.x);
  } else if (blk < 10240) {
    cast8(Wro, Wob, (size_t)(blk - 9728) * 256 + threadIdx.x);
  } else if (blk < 10752) {
    cast8(Wio, Wob + (size_t)1024 * 1024, (size_t)(blk - 10240) * 256 + threadIdx.x);
  } else {
    const int i = (blk - 10752) * 256 + threadIdx.x;
    if (i < D_DIM) bc[i] = br[i] + bi[i];
  }
}

// ---------------- shared GEMM pieces ----------------

__device__ __forceinline__ void readF(bf16x8 (&d)[2][2], const u16* s, int rowoff, int la32, int puA) {
#pragma unroll
  for (int mf = 0; mf < 2; ++mf)
#pragma unroll
    for (int kk = 0; kk < 2; ++kk)
      d[mf][kk] = *(const bf16x8*)(s + (rowoff + mf * 32 + la32) * 32 + (puA ^ (kk << 4)));
}

__device__ __forceinline__ void mfma8(f32x16 (&acc)[4][2], const bf16x8 (&a)[2][2],
                                      const bf16x8 (&b)[2][2], int QM) {
#pragma unroll
  for (int kk = 0; kk < 2; ++kk)
#pragma unroll
    for (int mf = 0; mf < 2; ++mf)
#pragma unroll
      for (int nf = 0; nf < 2; ++nf)
        acc[QM * 2 + mf][nf] =
            __builtin_amdgcn_mfma_f32_32x32x16_bf16(a[mf][kk], b[nf][kk], acc[QM * 2 + mf][nf], 0, 0, 0);
}

// ------- gemm1 variant: A from f32 GLOBAL via reg-staging (kills the x-cast pass) -------
// 256x256 tile, 8 waves, BK=64, 2-buffer 1-deep pipeline (round-3 shape, proven-simple).
// A: 8 x dwordx4 f32 loads -> f2bf (same RNE as cast kernel -> bit-identical values) ->
//    4 x ds_write_b128 at the SAME LDS addresses gload16 used (swizzle/read side unchanged).
// B: 4 x gload16 from bf16 Wc (unchanged).
// vmem/iter = 12 (8 A + 4 B). VM12 at iter end drains exactly B(t+1) while tile t+2 flies.
// cvt's compiler reg-dep wait covers A (issued one full tile earlier -> latency covered).
// LGK0 publishes ds_writes before each barrier.
// Tail: clamp t to 0 (dummy traffic to never-again-read regions; keeps vmcnt queue exact).
__global__ __launch_bounds__(512, 2) void gemm_f32a_kernel(
    const float* __restrict__ A0f, const float* __restrict__ A1f, int kSplit, int lda,
    const u16* __restrict__ Bw, int ldb,
    const float* __restrict__ bias,
    u16* __restrict__ C0, int ldc, int K, int nColBlk)
{
  extern __shared__ u16 lds[];   // 2 x (A 16KB | B 16KB) = 64 KB used (128 KB reserved)
  const int tid  = threadIdx.x;
  const int lane = tid & 63;
  const int w    = tid >> 6;
  const int wr   = w >> 2;
  const int wc   = w & 3;

  const int bid   = blockIdx.x;
  const int xcd   = bid & 7;
  const int local = bid >> 3;
  const int rowL  = local / nColBlk;
  const int colB  = local - rowL * nColBlk;
  const size_t rowBase = (size_t)(xcd * 16 + rowL) * 256;
  const size_t colBase = (size_t)colB * 256;

  f32x16 acc[4][2];
#pragma unroll
  for (int i = 0; i < 4; ++i)
#pragma unroll
    for (int j = 0; j < 2; ++j)
#pragma unroll
      for (int e = 0; e < 16; ++e) acc[i][j][e] = 0.f;

  const int NT = K >> 6;
  const int la32 = lane & 31;
  const int g2   = lane >> 5;
  const int f    = (la32 & 3) ^ ((la32 >> 2) & 3);
  const int puA  = ((g2 ^ f) << 3);

  float4 ar[8];   // one tile's A elems: [ks*4 + i2*2 + j]

  auto aload = [&](int t) {
    if (t >= NT) t = 0;
    const int kb = t * 64;
    const float* Af; int kc;
    if (kb < kSplit) { Af = A0f; kc = kb; } else { Af = A1f; kc = kb - kSplit; }
#pragma unroll
    for (int ks = 0; ks < 2; ++ks)
#pragma unroll
      for (int i2 = 0; i2 < 2; ++i2) {
        const int l = i2 * 512 + tid, r = l >> 2, p = l & 3;
        const int lu = p ^ (r & 3) ^ ((r >> 2) & 3);
        const float* g = Af + (rowBase + r) * (size_t)lda + kc + ks * 32 + lu * 8;
        ar[ks * 4 + i2 * 2 + 0] = *(const float4*)g;
        ar[ks * 4 + i2 * 2 + 1] = *(const float4*)(g + 4);
      }
  };
  auto cwrite = [&](int buf) {   // cvt + ds_write (reads ar -> compiler waits the A loads)
#pragma unroll
    for (int ks = 0; ks < 2; ++ks)
#pragma unroll
      for (int i2 = 0; i2 < 2; ++i2) {
        const int l = i2 * 512 + tid;
        const float4 x0 = ar[ks * 4 + i2 * 2 + 0];
        const float4 x1 = ar[ks * 4 + i2 * 2 + 1];
        union { u16 h[8]; uint4 u; } o;
        o.h[0] = f2bf(x0.x); o.h[1] = f2bf(x0.y); o.h[2] = f2bf(x0.z); o.h[3] = f2bf(x0.w);
        o.h[4] = f2bf(x1.x); o.h[5] = f2bf(x1.y); o.h[6] = f2bf(x1.z); o.h[7] = f2bf(x1.w);
        *(uint4*)(lds + buf * 32768 + ks * 8192 + (size_t)l * 8) = o.u;
      }
  };
  auto bgload = [&](int buf, int t) {
    if (t >= NT) t = 0;
    const int kb = t * 64;
#pragma unroll
    for (int ks = 0; ks < 2; ++ks)
#pragma unroll
      for (int i2 = 0; i2 < 2; ++i2) {
        const int l = i2 * 512 + tid, r = l >> 2, p = l & 3;
        const int lu = p ^ (r & 3) ^ ((r >> 2) & 3);
        gload16(Bw + (colBase + r) * (size_t)ldb + kb + ks * 32 + lu * 8,
                lds + buf * 32768 + 16384 + ks * 8192 + (size_t)l * 8);
      }
  };

  const int rA0 = wr * 128;
  const int rA1 = wr * 128 + 64;
  const int rB  = wc * 64;

  // prologue: tile0 (A regs + B gload + cvt_write), tile1 issued; drain B(t0)
  aload(0);
  bgload(0, 0);
  cwrite(0);                 // waits A(t0) [leaves B(t0) flying]
  aload(1);
  bgload(1, 1);
  SB(); VM12(); LGK0(); BAR(); SB();   // B(t0) done; A(t1)8+B(t1)4 = 12 in flight

  bf16x8 a0[2][2], a1[2][2], bb[2][2];
  for (int t = 0; t < NT; ++t) {
    const int cur = t & 1, o = cur ^ 1;
    const u16* sA = lds + cur * 32768;
    const u16* sBt = lds + cur * 32768 + 16384;
    // compute tile t (same per-acc k-order as the proven 8-phase kernel: ks0 kk01, ks1 kk01)
    readF(a0, sA, rA0, la32, puA);
    readF(a1, sA, rA1, la32, puA);
    readF(bb, sBt, rB, la32, puA);
    PRIO1(); mfma8(acc, a0, bb, 0); mfma8(acc, a1, bb, 1); PRIO0();
    readF(a0, sA + 8192, rA0, la32, puA);
    readF(a1, sA + 8192, rA1, la32, puA);
    readF(bb, sBt + 8192, rB, la32, puA);
    PRIO1(); mfma8(acc, a0, bb, 0); mfma8(acc, a1, bb, 1); PRIO0();
    SB(); BAR(); SB();
    // stage ahead: A(t+1) regs -> b[o].A ; issue A(t+2), B(t+2 -> b[cur].B)
    cwrite(o);               // ar holds A(t+1); waits its loads (leaves B(t+1) flying)
    aload(t + 2);            // reg WAR after cwrite's reads (in-wave order)
    bgload(cur, t + 2);      // b[cur].B was read above; barrier passed
    SB(); VM12(); LGK0(); BAR(); SB();   // drains B(t+1); A(t+2)+B(t+2)=12 fly
  }

  // epilogue: bf16 out + bias (EPI==1 semantics), single C0
#pragma unroll
  for (int mi = 0; mi < 4; ++mi)
#pragma unroll
    for (int ni = 0; ni < 2; ++ni) {
      const int cn = wc * 64 + ni * 32 + la32;
      const float badd = bias[colBase + cn];
      const size_t col = colBase + cn;
#pragma unroll
      for (int r = 0; r < 16; ++r) {
        const size_t row = rowBase + wr * 128 + mi * 32 + (r & 3) + 8 * (r >> 2) + 4 * g2;
        C0[row * (size_t)ldc + col] = f2bf(acc[mi][ni][r] + badd);
      }
    }
}

// ------- 256x256 8-phase bf16 MFMA GEMM (32x32x16), one-phase-ahead register pipeline -------
// Round-9 verified configuration (absmax bit-exact across rounds, 0 bank conflicts) — UNTOUCHED.

template <int EPI>
__global__ __launch_bounds__(512, 2) void gemm256_kernel(
    const u16* __restrict__ A0, const u16* __restrict__ A1, int kSplit, int lda,
    const u16* __restrict__ Bw, int ldb,
    const float* __restrict__ bias,
    void* __restrict__ C0, void* __restrict__ C1, void* __restrict__ C2,
    int ldc, int K, int nColBlk)
{
  extern __shared__ u16 lds[];   // 65536 u16 = 128 KB
  const int tid  = threadIdx.x;
  const int lane = tid & 63;
  const int w    = tid >> 6;
  const int wr   = w >> 2;
  const int wc   = w & 3;

  const int bid   = blockIdx.x;
  const int xcd   = bid & 7;
  const int local = bid >> 3;
  const int rowL  = local / nColBlk;
  const int colB  = local - rowL * nColBlk;
  const size_t rowBase = (size_t)(xcd * 16 + rowL) * 256;
  const size_t colBase = (size_t)colB * 256;

  f32x16 acc[4][2];
#pragma unroll
  for (int i = 0; i < 4; ++i)
#pragma unroll
    for (int j = 0; j < 2; ++j)
#pragma unroll
      for (int e = 0; e < 16; ++e) acc[i][j][e] = 0.f;

  const int NT = K >> 6;
  const int la32 = lane & 31;
  const int g2   = lane >> 5;
  const int f    = (la32 & 3) ^ ((la32 >> 2) & 3);
  const int puA  = ((g2 ^ f) << 3);

  auto stageA = [&](int buf, int ks, int t) {
    if (t >= NT) t = 0;   // dummy stage keeps vmcnt queue exact in the tail
    const int kb = t * 64;
    const u16* Ab; int kc;
    if (kb < kSplit) { Ab = A0; kc = kb; } else { Ab = A1; kc = kb - kSplit; }
    u16* dst = lds + buf * 32768 + ks * 8192;
#pragma unroll
    for (int i2 = 0; i2 < 2; ++i2) {
      const int l = i2 * 512 + tid, r = l >> 2, p = l & 3;
      const int lu = p ^ (r & 3) ^ ((r >> 2) & 3);
      gload16(Ab + (rowBase + r) * (size_t)lda + kc + ks * 32 + lu * 8, dst + l * 8);
    }
  };
  auto stageB = [&](int buf, int ks, int t) {
    if (t >= NT) t = 0;
    const int kb = t * 64;
    u16* dst = lds + buf * 32768 + 16384 + ks * 8192;
#pragma unroll
    for (int i2 = 0; i2 < 2; ++i2) {
      const int l = i2 * 512 + tid, r = l >> 2, p = l & 3;
      const int lu = p ^ (r & 3) ^ ((r >> 2) & 3);
      gload16(Bw + (colBase + r) * (size_t)ldb + kb + ks * 32 + lu * 8, dst + l * 8);
    }
  };

  const u16* sA_b0k0 = lds;
  const u16* sA_b0k1 = lds + 8192;
  const u16* sB_b0k0 = lds + 16384;
  const u16* sB_b0k1 = lds + 16384 + 8192;
  const u16* sA_b1k0 = lds + 32768;
  const u16* sA_b1k1 = lds + 32768 + 8192;
  const u16* sB_b1k0 = lds + 32768 + 16384;
  const u16* sB_b1k1 = lds + 32768 + 16384 + 8192;
  const int rA0 = wr * 128;
  const int rA1 = wr * 128 + 64;
  const int rB  = wc * 64;

  stageA(0, 0, 0); stageB(0, 0, 0); stageA(0, 1, 0); stageB(0, 1, 0);
  stageA(1, 0, 1); stageB(1, 0, 1);
  VM4();
  SB(); BAR(); SB();

  bf16x8 a0[2][2], a1[2][2], bbE[2][2], bbO[2][2];
  const int NIT = NT >> 1;
  for (int i = 0; i < NIT; ++i) {
    const int u = 2 * i, v = 2 * i + 1;
    readF(a0,  sA_b0k0, rA0, la32, puA);
    readF(bbE, sB_b0k0, rB,  la32, puA);
    readF(a1,  sA_b0k0, rA1, la32, puA);
    stageA(1, 1, v);
    SB(); BAR(); SB();
    PRIO1(); mfma8(acc, a0, bbE, 0); PRIO0(); SB();
    BAR(); SB();
    readF(a0,  sA_b0k1, rA0, la32, puA);
    readF(bbO, sB_b0k1, rB,  la32, puA);
    stageB(1, 1, v);
    SB(); BAR(); SB();
    PRIO1(); mfma8(acc, a1, bbE, 1); PRIO0(); SB();
    BAR(); SB();
    readF(a1,  sA_b0k1, rA1, la32, puA);
    stageA(0, 0, u + 2);
    SB(); BAR(); SB();
    PRIO1(); mfma8(acc, a0, bbO, 0); PRIO0(); SB();
    VM6();
    BAR(); SB();
    readF(a0,  sA_b1k0, rA0, la32, puA);
    readF(bbE, sB_b1k0, rB,  la32, puA);
    stageB(0, 0, u + 2);
    SB(); BAR(); SB();
    PRIO1(); mfma8(acc, a1, bbO, 1); PRIO0(); SB();
    VM4();
    BAR(); SB();
    readF(a1,  sA_b1k0, rA1, la32, puA);
    stageA(0, 1, u + 2);
    SB(); BAR(); SB();
    PRIO1(); mfma8(acc, a0, bbE, 0); PRIO0(); SB();
    BAR(); SB();
    readF(a0,  sA_b1k1, rA0, la32, puA);
    readF(bbO, sB_b1k1, rB,  la32, puA);
    stageB(0, 1, u + 2);
    SB(); BAR(); SB();
    PRIO1(); mfma8(acc, a1, bbE, 1); PRIO0(); SB();
    BAR(); SB();
    readF(a1,  sA_b1k1, rA1, la32, puA);
    stageA(1, 0, v + 2);
    SB(); BAR(); SB();
    PRIO1(); mfma8(acc, a0, bbO, 0); PRIO0(); SB();
    BAR(); SB();
    stageB(1, 0, v + 2);
    SB(); BAR(); SB();
    PRIO1(); mfma8(acc, a1, bbO, 1); PRIO0(); SB();
    VM4();
    BAR(); SB();
  }

  const int seg = (int)(colBase >> 10);
  const size_t colSeg = colBase & 1023;
  void* Cout;
  if (EPI == 3)      Cout = (seg == 0) ? C0 : (seg == 1) ? C1 : C2;
  else if (EPI == 2) Cout = (seg == 0) ? C0 : C1;
  else               Cout = C0;

#pragma unroll
  for (int mi = 0; mi < 4; ++mi)
#pragma unroll
    for (int ni = 0; ni < 2; ++ni) {
      const int cn = wc * 64 + ni * 32 + la32;
      const float badd = (EPI == 1) ? bias[colBase + cn] : 0.0f;
      const size_t col = colSeg + cn;
#pragma unroll
      for (int r = 0; r < 16; ++r) {
        const size_t row = rowBase + wr * 128 + mi * 32 + (r & 3) + 8 * (r >> 2) + 4 * g2;
        const float v = acc[mi][ni][r] + badd;
        if (EPI == 2) ((float*)Cout)[row * (size_t)ldc + col] = v;
        else          ((u16*)Cout)[row * (size_t)ldc + col] = f2bf(v);
      }
    }
}

// ---------------- LayerNorm (in-place on bf16 rows) ----------------

__global__ __launch_bounds__(256) void ln_kernel(u16* __restrict__ xc,
    const float* __restrict__ gamma, const float* __restrict__ beta)
{
  const size_t row = blockIdx.x;
  u16* p = xc + row * D_DIM;
  const int tid = threadIdx.x;
  const int c = tid * 4;
  const uint2 raw = *(const uint2*)(p + c);
  const float v0 = bf2f((u16)(raw.x & 0xffff)), v1 = bf2f((u16)(raw.x >> 16));
  const float v2 = bf2f((u16)(raw.y & 0xffff)), v3 = bf2f((u16)(raw.y >> 16));
  float s = v0 + v1 + v2 + v3;
  float q = v0 * v0 + v1 * v1 + v2 * v2 + v3 * v3;
#pragma unroll
  for (int o = 32; o > 0; o >>= 1) { s += __shfl_xor(s, o); q += __shfl_xor(q, o); }
  __shared__ float red[8];
  if ((tid & 63) == 0) { red[(tid >> 6) * 2] = s; red[(tid >> 6) * 2 + 1] = q; }
  __syncthreads();
  s = red[0] + red[2] + red[4] + red[6];
  q = red[1] + red[3] + red[5] + red[7];
  const float mu = s * (1.0f / D_DIM);
  const float var = q * (1.0f / D_DIM) - mu * mu;
  const float rstd = 1.0f / sqrtf(var + 1e-5f);
  const float y0 = (v0 - mu) * rstd * gamma[c] + beta[c];
  const float y1 = (v1 - mu) * rstd * gamma[c + 1] + beta[c + 1];
  const float y2 = (v2 - mu) * rstd * gamma[c + 2] + beta[c + 2];
  const float y3 = (v3 - mu) * rstd * gamma[c + 3] + beta[c + 3];
  const uint32_t o0 = (uint32_t)f2bf(y0) | ((uint32_t)f2bf(y1) << 16);
  const uint32_t o1 = (uint32_t)f2bf(y2) | ((uint32_t)f2bf(y3) << 16);
  *(uint2*)(p + c) = make_uint2(o0, o1);
}

// ------- FUSED gate + scan1 (independent after QKV; co-resident in one dispatch) -------
// blocks [0, 65536): gate[row,h] = sigmoid(q.k/sqrt(DH)) — one wave per (row,h)
// blocks [65536, 66560): scan1 — chunk-local EMA end states (carry[8][B*D])
// Disjoint inputs (Q,K vs V) and outputs (gate vs carry); block-uniform branch.

__global__ __launch_bounds__(256) void gate_scan1_kernel(
    const u16* __restrict__ Q, const u16* __restrict__ Kb, float* __restrict__ gate,
    const u16* __restrict__ vb, const float* __restrict__ log_alpha,
    float* __restrict__ carry)
{
  int blk = blockIdx.x;
  if (blk < 65536) {
    const int gw = blk * 4 + (threadIdx.x >> 6);   // wave id: row*8 + h
    const int lane = threadIdx.x & 63;
    const size_t row = (size_t)(gw >> 3);
    const int h = gw & 7;
    const size_t off = row * D_DIM + h * DH_DIM + lane * 2;
    const uint32_t qr = *(const uint32_t*)(Q + off);
    const uint32_t kr = *(const uint32_t*)(Kb + off);
    float d = bf2f((u16)(qr & 0xffff)) * bf2f((u16)(kr & 0xffff))
            + bf2f((u16)(qr >> 16))    * bf2f((u16)(kr >> 16));
#pragma unroll
    for (int o = 32; o > 0; o >>= 1) d += __shfl_xor(d, o);
    if (lane == 0) {
      const float x = d * 0.08838834764831845f;  // 1/sqrt(128)
      gate[gw] = 1.0f / (1.0f + expf(-x));
    }
  } else {
    blk -= 65536;
    const int j  = blk >> 7;                         // chunk 0..7
    const int th = (blk & 127) * 256 + threadIdx.x;  // 0..32767
    const int gid = th * 2;                          // b*1024 + c (even)
    const int b = gid >> 10;
    const int c = gid & 1023;
    const int h = c >> 7;
    const float alpha = 1.0f / (1.0f + expf(-log_alpha[h]));
    const float oma = 1.0f - alpha;
    const u16* vp = vb + ((size_t)(4096 * j + b)) * 1024 + c;
    float s0 = 0.f, s1 = 0.f;
#pragma unroll 8
    for (int i = 0; i < 64; ++i) {
      const uint32_t uv = *(const uint32_t*)(vp + (size_t)i * 65536);
      s0 = alpha * bf2f((u16)(uv & 0xffff)) + oma * s0;
      s1 = alpha * bf2f((u16)(uv >> 16))    + oma * s1;
    }
    *(float2*)(carry + (size_t)j * 65536 + gid) = make_float2(s0, s1);
  }
}

// ---------------- scan2: replay chunks with true carry ----------------

__global__ __launch_bounds__(256) void scan2_kernel(
    const u16* __restrict__ vb, const float* __restrict__ gate,
    const float* __restrict__ vstate, const float* __restrict__ log_alpha,
    const float* __restrict__ carry,
    u16* __restrict__ ret, float* __restrict__ fstate)
{
  const int j  = blockIdx.x >> 7;
  const int th = (blockIdx.x & 127) * 256 + threadIdx.x;
  const int gid = th * 2;
  const int b = gid >> 10;
  const int c = gid & 1023;
  const int h = c >> 7;
  const float alpha = 1.0f / (1.0f + expf(-log_alpha[h]));
  const float oma = 1.0f - alpha;
  float o64 = oma;
#pragma unroll
  for (int q = 0; q < 6; ++q) o64 *= o64;   // oma^64
  float s0 = vstate[gid], s1 = vstate[gid + 1];
  for (int i = 0; i < j; ++i) {
    const float2 L = *(const float2*)(carry + (size_t)i * 65536 + gid);
    s0 = L.x + o64 * s0;
    s1 = L.y + o64 * s1;
  }
  const u16* vp = vb + ((size_t)(4096 * j + b)) * 1024 + c;
  u16* rp = ret + ((size_t)(4096 * j + b)) * 1024 + c;
  const float* gp = gate + (size_t)(4096 * j + b) * H_DIM + h;
#pragma unroll 4
  for (int i = 0; i < 64; ++i) {
    const uint32_t uv = *(const uint32_t*)(vp + (size_t)i * 65536);
    const float g = gp[(size_t)i * 512];
    s0 = alpha * bf2f((u16)(uv & 0xffff)) + oma * s0;
    s1 = alpha * bf2f((u16)(uv >> 16))    + oma * s1;
    const uint32_t o = (uint32_t)f2bf(g * s0) | ((uint32_t)f2bf(g * s1) << 16);
    *(uint32_t*)(rp + (size_t)i * 65536) = o;
  }
  if (j == 7) { fstate[gid] = s0; fstate[gid + 1] = s1; }
}

// ---------------- launch ----------------

extern "C" void kernel_launch(void* const* d_in, const int* in_sizes, int n_in,
                              void* d_out, int out_size, void* d_ws, size_t ws_size,
                              hipStream_t stream) {
  const float* x_real      = (const float*)d_in[0];
  const float* x_imag      = (const float*)d_in[1];
  const float* value_state = (const float*)d_in[2];
  const float* Wr_in  = (const float*)d_in[4];
  const float* Wi_in  = (const float*)d_in[5];
  const float* br_in  = (const float*)d_in[6];
  const float* bi_in  = (const float*)d_in[7];
  const float* ln_g   = (const float*)d_in[8];
  const float* ln_b   = (const float*)d_in[9];
  const float* W_qkv  = (const float*)d_in[10];
  const float* log_alpha = (const float*)d_in[11];
  const float* Wr_out = (const float*)d_in[12];
  const float* Wi_out = (const float*)d_in[13];

  float* out_real = (float*)d_out;
  float* out_imag = out_real + (size_t)MROWS * D_DIM;
  float* fstate   = out_imag + (size_t)MROWS * D_DIM;

  u16* R0a = (u16*)d_out;                                        // Q (gemm3 output)
  u16* xc  = (u16*)((char*)d_out + (size_t)MROWS * D_DIM * 2);   // proj out, LN'd
  u16* Vb  = (u16*)out_imag;                                     // V

  char* ws = (char*)d_ws;
  size_t off = 0;
  auto alloc = [&](size_t bytes) { void* p = ws + off; off += (bytes + 255) & ~(size_t)255; return p; };
  u16*   Wc    = (u16*)alloc((size_t)1024 * 2048 * 2);
  u16*   Wqkvb = (u16*)alloc((size_t)3072 * 1024 * 2);
  u16*   Wob   = (u16*)alloc((size_t)2048 * 1024 * 2);
  float* bc    = (float*)alloc((size_t)D_DIM * 4);
  u16*   R0b   = (u16*)alloc((size_t)MROWS * D_DIM * 2); // K -> retrieved
  float* gate  = (float*)alloc((size_t)MROWS * H_DIM * 4);
  float* carry = (float*)alloc((size_t)8 * B_DIM * D_DIM * 4);

  const int LDSB = 131072;
  hipFuncSetAttribute((const void*)gemm_f32a_kernel,  hipFuncAttributeMaxDynamicSharedMemorySize, LDSB);
  hipFuncSetAttribute((const void*)gemm256_kernel<2>, hipFuncAttributeMaxDynamicSharedMemorySize, LDSB);
  hipFuncSetAttribute((const void*)gemm256_kernel<3>, hipFuncAttributeMaxDynamicSharedMemorySize, LDSB);

  // weight prep only (x casts eliminated)
  prep_cast_kernel<<<10756, 256, 0, stream>>>(Wr_in, Wi_in, br_in, bi_in, W_qkv, Wr_out, Wi_out,
                                              Wc, bc, Wqkvb, Wob);

  // input proj straight from f32 x: xc_pre = [xr|xi] @ Wc^T + bc
  gemm_f32a_kernel<<<dim3(128 * 4), 512, LDSB, stream>>>(
      x_real, x_imag, 1024, 1024, Wc, 2048, bc, xc, 1024, 2048, 4);
  // LayerNorm in place
  ln_kernel<<<MROWS, 256, 0, stream>>>(xc, ln_g, ln_b);
  // QKV in ONE GEMM (N=3072): Q -> R0a, K -> R0b, V -> Vb
  gemm256_kernel<3><<<dim3(128 * 12), 512, LDSB, stream>>>(
      xc, xc, 1024, 1024, Wqkvb, 1024, nullptr, R0a, R0b, Vb, 1024, 1024, 12);
  // gate (from Q,K) + scan1 chunk-carries (from V) — independent, fused into ONE dispatch
  gate_scan1_kernel<<<65536 + 1024, 256, 0, stream>>>(R0a, R0b, gate, Vb, log_alpha, carry);
  // scan2: replay with true carry -> retrieved in R0b
  scan2_kernel<<<1024, 256, 0, stream>>>(Vb, gate, value_state, log_alpha, carry, R0b, fstate);
  // output projections in ONE GEMM (N=2048, f32 out)
  gemm256_kernel<2><<<dim3(128 * 8), 512, LDSB, stream>>>(
      R0b, R0b, 1024, 1024, Wob, 1024, nullptr, out_real, out_imag, nullptr, 1024, 1024, 8);
}